// Round 3
// baseline (991.205 us; speedup 1.0000x reference)
//
#include <hip/hip_runtime.h>
#include <hip/hip_bf16.h>
#include <stdint.h>

using bf16 = __hip_bfloat16;

typedef __bf16 bf16x8 __attribute__((ext_vector_type(8)));
typedef float  f32x4  __attribute__((ext_vector_type(4)));

__device__ __forceinline__ float bflo(uint32_t u) { return __uint_as_float(u << 16); }
__device__ __forceinline__ float bfhi(uint32_t u) { return __uint_as_float(u & 0xffff0000u); }

__device__ __forceinline__ void load8(const bf16* p, float* f) {
  uint4 u = *(const uint4*)p;
  f[0] = bflo(u.x); f[1] = bfhi(u.x);
  f[2] = bflo(u.y); f[3] = bfhi(u.y);
  f[4] = bflo(u.z); f[5] = bfhi(u.z);
  f[6] = bflo(u.w); f[7] = bfhi(u.w);
}
__device__ __forceinline__ void load8(const float* p, float* f) {
  float4 a = *(const float4*)p, b = *(const float4*)(p + 4);
  f[0] = a.x; f[1] = a.y; f[2] = a.z; f[3] = a.w;
  f[4] = b.x; f[5] = b.y; f[6] = b.z; f[7] = b.w;
}
__device__ __forceinline__ void store1(float* o, float v) { *o = v; }
__device__ __forceinline__ void store1(bf16* o, float v) { *o = __float2bfloat16(v); }

// ---- tile staging into LDS (64x64 bf16), from bf16 or f32 source ----------
__device__ __forceinline__ void stage_tile(bf16 (*dst)[64], const bf16* src,
                                           int ldK, int t) {
#pragma unroll
  for (int c = 0; c < 2; ++c) {
    int idx = t + c * 256;
    int row = idx >> 3, ko = (idx & 7) * 8;
    *(uint4*)(&dst[row][ko]) = *(const uint4*)(src + (size_t)row * ldK + ko);
  }
}
__device__ __forceinline__ void stage_tile(bf16 (*dst)[64], const float* src,
                                           int ldK, int t) {
#pragma unroll
  for (int c = 0; c < 4; ++c) {
    int idx = t + c * 256;
    int row = idx >> 4, c4 = (idx & 15) * 4;
    float4 v = *(const float4*)(src + (size_t)row * ldK + c4);
    bf16* d = &dst[row][c4];
    d[0] = __float2bfloat16(v.x); d[1] = __float2bfloat16(v.y);
    d[2] = __float2bfloat16(v.z); d[3] = __float2bfloat16(v.w);
  }
}

// ---------------------------------------------------------------------------
// GEMM: C[M,Nout] = A[M,K] * W[Nout,K]^T + bias  (bf16 MFMA, f32 accum)
// A: f32 or bf16. W,bias: f32. out: bf16.
// MODE 0: store. MODE 1: relu+store. MODE 2: QKV scatter to [which][b][h][n][d]
// ---------------------------------------------------------------------------
template<int MODE, typename TA>
__global__ __launch_bounds__(256)
void gemm_bt(const TA* __restrict__ A, const float* __restrict__ W,
             const float* __restrict__ bias, bf16* __restrict__ outb,
             int M, int Nout, int K)
{
  __shared__ bf16 As[64][64];
  __shared__ bf16 Bs[64][64];
  const int t = threadIdx.x;
  const int lane = t & 63, wave = t >> 6;
  const int m0 = blockIdx.y * 64, n0 = blockIdx.x * 64;
  const int wm = (wave >> 1) * 32, wn = (wave & 1) * 32;
  const int frow = lane & 15, ksel = (lane >> 4) * 8;
  f32x4 acc00 = {0.f,0.f,0.f,0.f}, acc01 = {0.f,0.f,0.f,0.f};
  f32x4 acc10 = {0.f,0.f,0.f,0.f}, acc11 = {0.f,0.f,0.f,0.f};

  for (int k0 = 0; k0 < K; k0 += 64) {
    __syncthreads();
    stage_tile(As, A + (size_t)m0 * K + k0, K, t);
    stage_tile(Bs, W + (size_t)n0 * K + k0, K, t);
    __syncthreads();
#pragma unroll
    for (int kk = 0; kk < 64; kk += 32) {
      bf16x8 a0 = *(const bf16x8*)(&As[wm +      frow][kk + ksel]);
      bf16x8 a1 = *(const bf16x8*)(&As[wm + 16 + frow][kk + ksel]);
      bf16x8 b0 = *(const bf16x8*)(&Bs[wn +      frow][kk + ksel]);
      bf16x8 b1 = *(const bf16x8*)(&Bs[wn + 16 + frow][kk + ksel]);
      acc00 = __builtin_amdgcn_mfma_f32_16x16x32_bf16(a0, b0, acc00, 0, 0, 0);
      acc01 = __builtin_amdgcn_mfma_f32_16x16x32_bf16(a0, b1, acc01, 0, 0, 0);
      acc10 = __builtin_amdgcn_mfma_f32_16x16x32_bf16(a1, b0, acc10, 0, 0, 0);
      acc11 = __builtin_amdgcn_mfma_f32_16x16x32_bf16(a1, b1, acc11, 0, 0, 0);
    }
  }
  const int rb = (lane >> 4) * 4, cb = lane & 15;
#pragma unroll
  for (int mt = 0; mt < 2; ++mt) {
#pragma unroll
    for (int nt = 0; nt < 2; ++nt) {
      f32x4 a = (mt == 0) ? ((nt == 0) ? acc00 : acc01)
                          : ((nt == 0) ? acc10 : acc11);
#pragma unroll
      for (int r = 0; r < 4; ++r) {
        int row = m0 + wm + mt * 16 + rb + r;
        int col = n0 + wn + nt * 16 + cb;
        float v = a[r] + bias[col];
        if (MODE == 1) v = fmaxf(v, 0.f);
        if (MODE == 2) {
          // col -> (which, h, d); row = n*4 + b.  dst: [which][b][h][n][d]
          int which = col >> 9, hh = (col >> 6) & 7, d = col & 63;
          int n = row >> 2, b = row & 3;
          outb[((((size_t)which * 4 + b) * 8 + hh) * 1024 + n) * 64 + d] = __float2bfloat16(v);
        } else {
          outb[(size_t)row * Nout + col] = __float2bfloat16(v);
        }
      }
    }
  }
}

// ---------------------------------------------------------------------------
// parent/child bias projections: pb[b,h,n] = x[n,b,:].Wp[h,:] + bp[h]
// ---------------------------------------------------------------------------
__global__ __launch_bounds__(256)
void pbcb_kernel(const float* __restrict__ x, const float* __restrict__ Wp,
                 const float* __restrict__ bp, const float* __restrict__ Wc,
                 const float* __restrict__ bc, float* __restrict__ pbo,
                 float* __restrict__ cbo)
{
  const int wave = threadIdx.x >> 6, lane = threadIdx.x & 63;
  const int m = blockIdx.x * 4 + wave;     // m = n*4 + b
  float xv[8];
  load8(x + (size_t)m * 512 + lane * 8, xv);
  const int n = m >> 2, b = m & 3;
#pragma unroll
  for (int hh = 0; hh < 8; ++hh) {
    float wp[8], wc[8];
    load8(Wp + (size_t)hh * 512 + lane * 8, wp);
    load8(Wc + (size_t)hh * 512 + lane * 8, wc);
    float ap = 0.f, ac = 0.f;
#pragma unroll
    for (int j = 0; j < 8; ++j) { ap += xv[j] * wp[j]; ac += xv[j] * wc[j]; }
#pragma unroll
    for (int off = 32; off; off >>= 1) {
      ap += __shfl_xor(ap, off);
      ac += __shfl_xor(ac, off);
    }
    if (lane == 0) {
      pbo[((size_t)b * 8 + hh) * 1024 + n] = ap + bp[hh];
      cbo[((size_t)b * 8 + hh) * 1024 + n] = ac + bc[hh];
    }
  }
}

// ---------------------------------------------------------------------------
// parent_mask transpose per batch: pmT[b,i,j] = pm[b,j,i]  (f32 -> bf16)
// ---------------------------------------------------------------------------
__global__ __launch_bounds__(256)
void transpose_pm(const float* __restrict__ pm, bf16* __restrict__ pmT)
{
  __shared__ bf16 tile[64][65];
  const int b = blockIdx.z;
  const int x0 = blockIdx.x * 64, y0 = blockIdx.y * 64;
  const size_t base = (size_t)b * 1024 * 1024;
  for (int i = threadIdx.x; i < 4096; i += 256) {
    int r = i >> 6, c = i & 63;
    tile[r][c] = __float2bfloat16(pm[base + (size_t)(y0 + r) * 1024 + x0 + c]);
  }
  __syncthreads();
  for (int i = threadIdx.x; i < 4096; i += 256) {
    int r = i >> 6, c = i & 63;
    pmT[base + (size_t)(x0 + r) * 1024 + y0 + c] = tile[c][r];
  }
}

// ---------------------------------------------------------------------------
// Fused flash-style attention. Block = (16 q-rows, one (b,h)). 256 thr.
// qkv: bf16 [3][B][H][N][64] (ours), f32 in LDS. Online softmax.
// K/V tiles of 128 in LDS with XOR chunk swizzle (chunk ^= (row>>1)&15).
// pm: f32 input. pmT: bf16 (ours). hid/padm: int32.
// ---------------------------------------------------------------------------
__global__ __launch_bounds__(256)
void attn_fused(const bf16* __restrict__ qkv, const float* __restrict__ pbw,
                const float* __restrict__ cbw, const float* __restrict__ pm,
                const bf16* __restrict__ pmT, const int* __restrict__ hid,
                const int* __restrict__ padm, bf16* __restrict__ ctxo)
{
  const int q0 = blockIdx.x * 16;
  const int h = blockIdx.y, b = blockIdx.z;
  const int t = threadIdx.x, lane = t & 63, wave = t >> 6;
  __shared__ float Kt[128 * 64];
  __shared__ float St[16][128];
  __shared__ float Qs[16][68];
  const size_t bh = (size_t)b * 8 + h;
  const bf16* Qp = qkv + bh * (1024 * 64);
  const bf16* Kp = qkv + (32 + bh) * (1024 * 64);
  const bf16* Vp = qkv + (64 + bh) * (1024 * 64);
  {
    int r = t >> 4, c4 = t & 15;
    uint2 u = *(const uint2*)(Qp + (size_t)(q0 + r) * 64 + c4 * 4);
    float4 q4 = { bflo(u.x), bfhi(u.x), bflo(u.y), bfhi(u.y) };
    *(float4*)&Qs[r][c4 * 4] = q4;
  }
  float pbv[4], cbv[4];
#pragma unroll
  for (int i = 0; i < 4; ++i) {
    int qg = q0 + wave * 4 + i;
    pbv[i] = pbw[bh * 1024 + qg];
    cbv[i] = cbw[bh * 1024 + qg];
  }
  float cacc[4] = {0.f, 0.f, 0.f, 0.f};
  float mrow[4] = {-1e30f, -1e30f, -1e30f, -1e30f};
  float lrow[4] = {0.f, 0.f, 0.f, 0.f};

  for (int kt = 0; kt < 8; ++kt) {
    const int k0 = kt * 128;
    __syncthreads();                      // previous ctx done with Kt
#pragma unroll
    for (int i = 0; i < 4; ++i) {        // stage K tile (bf16 -> f32, swizzled)
      int idx = t + i * 256;
      int r = idx >> 3, c8 = idx & 7;
      uint4 u = *(const uint4*)(Kp + (size_t)(k0 + r) * 64 + c8 * 8);
      float4 lo = { bflo(u.x), bfhi(u.x), bflo(u.y), bfhi(u.y) };
      float4 hi = { bflo(u.z), bfhi(u.z), bflo(u.w), bfhi(u.w) };
      int sw = (r >> 1) & 15;
      *(float4*)&Kt[r * 64 + (((2 * c8    ) ^ sw) << 2)] = lo;
      *(float4*)&Kt[r * 64 + (((2 * c8 + 1) ^ sw) << 2)] = hi;
    }
    __syncthreads();
    // ---- scores: wave handles rows wave*4..+3, lane handles cols 2*lane,+1
    {
      const int kk0 = lane * 2;
      const int x0 = lane & 15;          // (kk0>>1)&15 == ((kk0+1)>>1)&15
      float sacc[4][2] = {{0,0},{0,0},{0,0},{0,0}};
#pragma unroll
      for (int d4 = 0; d4 < 16; ++d4) {
        float4 kv0 = *(float4*)&Kt[(kk0    ) * 64 + ((d4 ^ x0) << 2)];
        float4 kv1 = *(float4*)&Kt[(kk0 + 1) * 64 + ((d4 ^ x0) << 2)];
#pragma unroll
        for (int i = 0; i < 4; ++i) {
          float4 qv = *(float4*)&Qs[wave * 4 + i][d4 * 4];
          sacc[i][0] += qv.x*kv0.x + qv.y*kv0.y + qv.z*kv0.z + qv.w*kv0.w;
          sacc[i][1] += qv.x*kv1.x + qv.y*kv1.y + qv.z*kv1.z + qv.w*kv1.w;
        }
      }
      int2 pv = *(const int2*)(padm + (size_t)b * 1024 + k0 + kk0);
#pragma unroll
      for (int i = 0; i < 4; ++i) {
        int qg = q0 + wave * 4 + i;
        size_t mb = ((size_t)b * 1024 + qg) * 1024 + k0 + kk0;
        float2 pmv = *(const float2*)(pm + mb);
        uint32_t pmtu = *(const uint32_t*)(pmT + mb);
        int2 hv = *(const int2*)(hid + mb);
        float s0 = sacc[i][0] * 0.125f + bflo(pmtu) * pbv[i] + pmv.x * cbv[i];
        float s1 = sacc[i][1] * 0.125f + bfhi(pmtu) * pbv[i] + pmv.y * cbv[i];
        if (hv.x | pv.x) s0 = -1e30f;
        if (hv.y | pv.y) s1 = -1e30f;
        St[wave * 4 + i][kk0    ] = s0;
        St[wave * 4 + i][kk0 + 1] = s1;
      }
    }
    __syncthreads();
    // ---- online softmax (rows are wave-private; stats in regs via butterfly)
    float al[4];
#pragma unroll
    for (int rr = 0; rr < 4; ++rr) {
      int r = wave * 4 + rr;
      float s0 = St[r][lane * 2], s1 = St[r][lane * 2 + 1];
      float mx = fmaxf(s0, s1);
#pragma unroll
      for (int off = 32; off; off >>= 1) mx = fmaxf(mx, __shfl_xor(mx, off));
      float newm = fmaxf(mrow[rr], mx);
      float p0 = (s0 <= -1e29f) ? 0.f : __expf(s0 - newm);  // guard all-masked
      float p1 = (s1 <= -1e29f) ? 0.f : __expf(s1 - newm);
      St[r][lane * 2]     = p0;
      St[r][lane * 2 + 1] = p1;
      float ps = p0 + p1;
#pragma unroll
      for (int off = 32; off; off >>= 1) ps += __shfl_xor(ps, off);
      float a = __expf(mrow[rr] - newm);
      lrow[rr] = lrow[rr] * a + ps;
      mrow[rr] = newm;
      al[rr] = a;
    }
#pragma unroll
    for (int i = 0; i < 4; ++i) cacc[i] *= al[i];
#pragma unroll
    for (int i = 0; i < 4; ++i) {        // stage V tile (bf16 -> f32, swizzled)
      int idx = t + i * 256;
      int r = idx >> 3, c8 = idx & 7;
      uint4 u = *(const uint4*)(Vp + (size_t)(k0 + r) * 64 + c8 * 8);
      float4 lo = { bflo(u.x), bfhi(u.x), bflo(u.y), bfhi(u.y) };
      float4 hi = { bflo(u.z), bfhi(u.z), bflo(u.w), bfhi(u.w) };
      int sw = (r >> 1) & 15;
      *(float4*)&Kt[r * 64 + (((2 * c8    ) ^ sw) << 2)] = lo;
      *(float4*)&Kt[r * 64 + (((2 * c8 + 1) ^ sw) << 2)] = hi;
    }
    __syncthreads();
    // ---- ctx accumulate: thread owns d=lane, rows wave*4..+3
    {
      const int dlo = lane & 3, dch = lane >> 2;
      const int rs = wave * 4;
#pragma unroll
      for (int k4 = 0; k4 < 32; ++k4) {
        float4 s0v = *(float4*)&St[rs + 0][k4 * 4];
        float4 s1v = *(float4*)&St[rs + 1][k4 * 4];
        float4 s2v = *(float4*)&St[rs + 2][k4 * 4];
        float4 s3v = *(float4*)&St[rs + 3][k4 * 4];
        int kr = k4 * 4;
        float v0 = Kt[(kr+0)*64 + (((dch ^ (((kr+0)>>1)&15)) << 2) | dlo)];
        float v1 = Kt[(kr+1)*64 + (((dch ^ (((kr+1)>>1)&15)) << 2) | dlo)];
        float v2 = Kt[(kr+2)*64 + (((dch ^ (((kr+2)>>1)&15)) << 2) | dlo)];
        float v3 = Kt[(kr+3)*64 + (((dch ^ (((kr+3)>>1)&15)) << 2) | dlo)];
        cacc[0] += s0v.x*v0 + s0v.y*v1 + s0v.z*v2 + s0v.w*v3;
        cacc[1] += s1v.x*v0 + s1v.y*v1 + s1v.z*v2 + s1v.w*v3;
        cacc[2] += s2v.x*v0 + s2v.y*v1 + s2v.z*v2 + s2v.w*v3;
        cacc[3] += s3v.x*v0 + s3v.y*v1 + s3v.z*v2 + s3v.w*v3;
      }
    }
  }
#pragma unroll
  for (int i = 0; i < 4; ++i) {
    int qg = q0 + wave * 4 + i;
    float o = (lrow[i] > 0.f) ? cacc[i] / lrow[i] : 0.f;   // NaN guard
    ctxo[((size_t)qg * 4 + b) * 512 + h * 64 + lane] = __float2bfloat16(o);
  }
}

// ---------------------------------------------------------------------------
// out = LayerNorm(a + rsd) * g + be   (row = 512 elems, wave per row)
// ---------------------------------------------------------------------------
template<typename TA, typename TR, typename TO>
__global__ __launch_bounds__(256)
void ln_res(const TA* __restrict__ a, const TR* __restrict__ rsd,
            const float* __restrict__ g, const float* __restrict__ be,
            TO* __restrict__ out)
{
  const int wave = threadIdx.x >> 6, lane = threadIdx.x & 63;
  const int m = blockIdx.x * 4 + wave;
  const size_t base = (size_t)m * 512 + lane * 8;
  float va[8], vb[8];
  load8(a + base, va);
  load8(rsd + base, vb);
  float v[8], s = 0.f;
#pragma unroll
  for (int j = 0; j < 8; ++j) { v[j] = va[j] + vb[j]; s += v[j]; }
#pragma unroll
  for (int off = 32; off; off >>= 1) s += __shfl_xor(s, off);
  const float mean = s * (1.f / 512.f);
  float q = 0.f;
#pragma unroll
  for (int j = 0; j < 8; ++j) { float d = v[j] - mean; q += d * d; }
#pragma unroll
  for (int off = 32; off; off >>= 1) q += __shfl_xor(q, off);
  const float rs = rsqrtf(q * (1.f / 512.f) + 1e-5f);
  float gv[8], bv[8];
  load8(g + lane * 8, gv);
  load8(be + lane * 8, bv);
#pragma unroll
  for (int j = 0; j < 8; ++j)
    store1(out + base + j, (v[j] - mean) * rs * gv[j] + bv[j]);
}

// ---------------------------------------------------------------------------
extern "C" void kernel_launch(void* const* d_in, const int* in_sizes, int n_in,
                              void* d_out, int out_size, void* d_ws, size_t ws_size,
                              hipStream_t stream)
{
  (void)in_sizes; (void)n_in; (void)out_size; (void)ws_size;
  const float* x    = (const float*)d_in[0];
  const float* pm   = (const float*)d_in[1];
  const int*   hid  = (const int*)d_in[2];
  const int*   padm = (const int*)d_in[3];
  const float* Wp   = (const float*)d_in[4];
  const float* bp   = (const float*)d_in[5];
  const float* Wc   = (const float*)d_in[6];
  const float* bc   = (const float*)d_in[7];
  const float* Wqkv = (const float*)d_in[8];
  const float* bqkv = (const float*)d_in[9];
  const float* Wo   = (const float*)d_in[10];
  const float* bo   = (const float*)d_in[11];
  const float* W1   = (const float*)d_in[12];
  const float* b1   = (const float*)d_in[13];
  const float* W2   = (const float*)d_in[14];
  const float* b2   = (const float*)d_in[15];
  const float* g1   = (const float*)d_in[16];
  const float* be1  = (const float*)d_in[17];
  const float* g2   = (const float*)d_in[18];
  const float* be2  = (const float*)d_in[19];

  // Workspace layout (max offset 33,816,576 B ~= 32.25 MiB; aliases noted)
  char* ws = (char*)d_ws;
  bf16*  qkvb  = (bf16*) (ws);               // 12,582,912 B: [3][B][H][N][64] bf16
  float* pbo   = (float*)(ws + 12582912);    //    131,072 B: [B][H][N] f32
  float* cbo   = (float*)(ws + 12713984);    //    131,072 B
  bf16*  pmT   = (bf16*) (ws + 12845056);    //  8,388,608 B: [B][N][N] bf16
  bf16*  ctx   = (bf16*) (ws + 21233664);    //  4,194,304 B: [M][512]
  bf16*  attno = (bf16*) (ws + 25427968);    //  4,194,304 B
  bf16*  y     = (bf16*) (ws + 29622272);    //  4,194,304 B  (ends 33,816,576)
  bf16*  ff1   = (bf16*) (ws);               // 16,777,216 B: aliases qkv+pb+cb+pmT-head (dead after attn)
  bf16*  ff2   = (bf16*) (ws + 21233664);    //  4,194,304 B: aliases ctx (dead after Wo gemm)

  transpose_pm<<<dim3(16, 16, 4), 256, 0, stream>>>(pm, pmT);
  pbcb_kernel<<<1024, 256, 0, stream>>>(x, Wp, bp, Wc, bc, pbo, cbo);
  gemm_bt<2, float><<<dim3(24, 64), 256, 0, stream>>>(x, Wqkv, bqkv, qkvb, 4096, 1536, 512);
  attn_fused<<<dim3(64, 8, 4), 256, 0, stream>>>(qkvb, pbo, cbo, pm, pmT, hid, padm, ctx);
  gemm_bt<0, bf16><<<dim3(8, 64), 256, 0, stream>>>(ctx, Wo, bo, attno, 4096, 512, 512);
  ln_res<float, bf16, bf16><<<1024, 256, 0, stream>>>(x, attno, g1, be1, y);
  gemm_bt<1, bf16><<<dim3(32, 64), 256, 0, stream>>>(y, W1, b1, ff1, 4096, 2048, 512);
  gemm_bt<0, bf16><<<dim3(8, 64), 256, 0, stream>>>(ff1, W2, b2, ff2, 4096, 512, 2048);
  ln_res<bf16, bf16, float><<<1024, 256, 0, stream>>>(y, ff2, g2, be2, (float*)d_out);
}

// Round 4
// 407.234 us; speedup vs baseline: 2.4340x; 2.4340x over previous
//
#include <hip/hip_runtime.h>
#include <hip/hip_bf16.h>
#include <stdint.h>

using bf16 = __hip_bfloat16;

typedef __bf16 bf16x8 __attribute__((ext_vector_type(8)));
typedef float  f32x4  __attribute__((ext_vector_type(4)));

__device__ __forceinline__ float bflo(uint32_t u) { return __uint_as_float(u << 16); }
__device__ __forceinline__ float bfhi(uint32_t u) { return __uint_as_float(u & 0xffff0000u); }

__device__ __forceinline__ void load8(const bf16* p, float* f) {
  uint4 u = *(const uint4*)p;
  f[0] = bflo(u.x); f[1] = bfhi(u.x);
  f[2] = bflo(u.y); f[3] = bfhi(u.y);
  f[4] = bflo(u.z); f[5] = bfhi(u.z);
  f[6] = bflo(u.w); f[7] = bfhi(u.w);
}
__device__ __forceinline__ void load8(const float* p, float* f) {
  float4 a = *(const float4*)p, b = *(const float4*)(p + 4);
  f[0] = a.x; f[1] = a.y; f[2] = a.z; f[3] = a.w;
  f[4] = b.x; f[5] = b.y; f[6] = b.z; f[7] = b.w;
}
__device__ __forceinline__ void store1(float* o, float v) { *o = v; }
__device__ __forceinline__ void store1(bf16* o, float v) { *o = __float2bfloat16(v); }

// ---- tile staging into LDS (64x64 bf16), from bf16 or f32 source ----------
__device__ __forceinline__ void stage_tile(bf16 (*dst)[64], const bf16* src,
                                           int ldK, int t) {
#pragma unroll
  for (int c = 0; c < 2; ++c) {
    int idx = t + c * 256;
    int row = idx >> 3, ko = (idx & 7) * 8;
    *(uint4*)(&dst[row][ko]) = *(const uint4*)(src + (size_t)row * ldK + ko);
  }
}
__device__ __forceinline__ void stage_tile(bf16 (*dst)[64], const float* src,
                                           int ldK, int t) {
#pragma unroll
  for (int c = 0; c < 4; ++c) {
    int idx = t + c * 256;
    int row = idx >> 4, c4 = (idx & 15) * 4;
    float4 v = *(const float4*)(src + (size_t)row * ldK + c4);
    bf16* d = &dst[row][c4];
    d[0] = __float2bfloat16(v.x); d[1] = __float2bfloat16(v.y);
    d[2] = __float2bfloat16(v.z); d[3] = __float2bfloat16(v.w);
  }
}

// ---------------------------------------------------------------------------
// GEMM: C[M,Nout] = A[M,K] * W[Nout,K]^T + bias  (bf16 MFMA, f32 accum)
// MODE 0: store. MODE 1: relu+store.
// MODE 2: QKV scatter: Q,K -> [which][b][h][n][d]; V -> transposed [b][h][d][n]
// ---------------------------------------------------------------------------
template<int MODE, typename TA>
__global__ __launch_bounds__(256)
void gemm_bt(const TA* __restrict__ A, const float* __restrict__ W,
             const float* __restrict__ bias, bf16* __restrict__ outb,
             int M, int Nout, int K)
{
  __shared__ bf16 As[64][64];
  __shared__ bf16 Bs[64][64];
  const int t = threadIdx.x;
  const int lane = t & 63, wave = t >> 6;
  const int m0 = blockIdx.y * 64, n0 = blockIdx.x * 64;
  const int wm = (wave >> 1) * 32, wn = (wave & 1) * 32;
  const int frow = lane & 15, ksel = (lane >> 4) * 8;
  f32x4 acc00 = {0.f,0.f,0.f,0.f}, acc01 = {0.f,0.f,0.f,0.f};
  f32x4 acc10 = {0.f,0.f,0.f,0.f}, acc11 = {0.f,0.f,0.f,0.f};

  for (int k0 = 0; k0 < K; k0 += 64) {
    __syncthreads();
    stage_tile(As, A + (size_t)m0 * K + k0, K, t);
    stage_tile(Bs, W + (size_t)n0 * K + k0, K, t);
    __syncthreads();
#pragma unroll
    for (int kk = 0; kk < 64; kk += 32) {
      bf16x8 a0 = *(const bf16x8*)(&As[wm +      frow][kk + ksel]);
      bf16x8 a1 = *(const bf16x8*)(&As[wm + 16 + frow][kk + ksel]);
      bf16x8 b0 = *(const bf16x8*)(&Bs[wn +      frow][kk + ksel]);
      bf16x8 b1 = *(const bf16x8*)(&Bs[wn + 16 + frow][kk + ksel]);
      acc00 = __builtin_amdgcn_mfma_f32_16x16x32_bf16(a0, b0, acc00, 0, 0, 0);
      acc01 = __builtin_amdgcn_mfma_f32_16x16x32_bf16(a0, b1, acc01, 0, 0, 0);
      acc10 = __builtin_amdgcn_mfma_f32_16x16x32_bf16(a1, b0, acc10, 0, 0, 0);
      acc11 = __builtin_amdgcn_mfma_f32_16x16x32_bf16(a1, b1, acc11, 0, 0, 0);
    }
  }
  const int rb = (lane >> 4) * 4, cb = lane & 15;
#pragma unroll
  for (int mt = 0; mt < 2; ++mt) {
#pragma unroll
    for (int nt = 0; nt < 2; ++nt) {
      f32x4 a = (mt == 0) ? ((nt == 0) ? acc00 : acc01)
                          : ((nt == 0) ? acc10 : acc11);
#pragma unroll
      for (int r = 0; r < 4; ++r) {
        int row = m0 + wm + mt * 16 + rb + r;
        int col = n0 + wn + nt * 16 + cb;
        float v = a[r] + bias[col];
        if (MODE == 1) v = fmaxf(v, 0.f);
        if (MODE == 2) {
          int which = col >> 9, hh = (col >> 6) & 7, d = col & 63;
          int n = row >> 2, b = row & 3;
          size_t idx;
          if (which == 2)   // V stored transposed: [b][h][d][n]
            idx = (((size_t)(64 + b * 8 + hh)) << 16) + (size_t)d * 1024 + n;
          else              // Q,K: [which][b][h][n][d]
            idx = (((size_t)(which * 32 + b * 8 + hh)) << 16) + (size_t)n * 64 + d;
          outb[idx] = __float2bfloat16(v);
        } else {
          outb[(size_t)row * Nout + col] = __float2bfloat16(v);
        }
      }
    }
  }
}

// ---------------------------------------------------------------------------
// parent/child bias projections: pb[b,h,n] = x[n,b,:].Wp[h,:] + bp[h]
// ---------------------------------------------------------------------------
__global__ __launch_bounds__(256)
void pbcb_kernel(const float* __restrict__ x, const float* __restrict__ Wp,
                 const float* __restrict__ bp, const float* __restrict__ Wc,
                 const float* __restrict__ bc, float* __restrict__ pbo,
                 float* __restrict__ cbo)
{
  const int wave = threadIdx.x >> 6, lane = threadIdx.x & 63;
  const int m = blockIdx.x * 4 + wave;     // m = n*4 + b
  float xv[8];
  load8(x + (size_t)m * 512 + lane * 8, xv);
  const int n = m >> 2, b = m & 3;
#pragma unroll
  for (int hh = 0; hh < 8; ++hh) {
    float wp[8], wc[8];
    load8(Wp + (size_t)hh * 512 + lane * 8, wp);
    load8(Wc + (size_t)hh * 512 + lane * 8, wc);
    float ap = 0.f, ac = 0.f;
#pragma unroll
    for (int j = 0; j < 8; ++j) { ap += xv[j] * wp[j]; ac += xv[j] * wc[j]; }
#pragma unroll
    for (int off = 32; off; off >>= 1) {
      ap += __shfl_xor(ap, off);
      ac += __shfl_xor(ac, off);
    }
    if (lane == 0) {
      pbo[((size_t)b * 8 + hh) * 1024 + n] = ap + bp[hh];
      cbo[((size_t)b * 8 + hh) * 1024 + n] = ac + bc[hh];
    }
  }
}

// ---------------------------------------------------------------------------
// parent_mask transpose per batch: pmT[b,i,j] = pm[b,j,i]  (f32 -> bf16)
// ---------------------------------------------------------------------------
__global__ __launch_bounds__(256)
void transpose_pm(const float* __restrict__ pm, bf16* __restrict__ pmT)
{
  __shared__ bf16 tile[64][65];
  const int b = blockIdx.z;
  const int x0 = blockIdx.x * 64, y0 = blockIdx.y * 64;
  const size_t base = (size_t)b * 1024 * 1024;
  for (int i = threadIdx.x; i < 4096; i += 256) {
    int r = i >> 6, c = i & 63;
    tile[r][c] = __float2bfloat16(pm[base + (size_t)(y0 + r) * 1024 + x0 + c]);
  }
  __syncthreads();
  for (int i = threadIdx.x; i < 4096; i += 256) {
    int r = i >> 6, c = i & 63;
    pmT[base + (size_t)(x0 + r) * 1024 + y0 + c] = tile[c][r];
  }
}

// ---------------------------------------------------------------------------
// MFMA flash attention. Block = 64 q-rows of one (b,h); 4 waves x 16 q-rows.
// K-tile = 128 keys. QK^T via 16x16x32 bf16 MFMA (NT form). PV computed as
// O^T = V^T * P (V stored transposed globally; P round-trips LDS as [q][k]).
// Online softmax in C-layout registers, butterfly over 16-lane groups.
// ---------------------------------------------------------------------------
__global__ __launch_bounds__(256, 3)
void attn_mfma(const bf16* __restrict__ qkv, const float* __restrict__ pbw,
               const float* __restrict__ cbw, const float* __restrict__ pm,
               const bf16* __restrict__ pmT, const int* __restrict__ hid,
               const int* __restrict__ padm, bf16* __restrict__ ctxo)
{
  __shared__ bf16 Kt[128][72];     // [key][d], +8 pad -> 2-way reads
  __shared__ bf16 Vt[64][136];     // [d][key], +8 pad
  __shared__ bf16 Ps[4][16][136];  // per-wave P [q_local][key], +8 pad
  const int t = threadIdx.x, lane = t & 63, wave = t >> 6;
  const int g = lane >> 4, c = lane & 15;
  const int h = blockIdx.y, b = blockIdx.z;
  const int q0 = blockIdx.x * 64 + wave * 16;   // this wave's 16 q rows
  const size_t bh = (size_t)b * 8 + h;
  const bf16* Qp = qkv + (bh << 16);
  const bf16* Kp = qkv + ((32 + bh) << 16);
  const bf16* Vg = qkv + ((64 + bh) << 16);     // [64 d][1024 n]

  // Q fragments (A-layout): lane holds Q[q0 + c][g*8 + j (+32)]
  bf16x8 qa0 = *(const bf16x8*)(Qp + (size_t)(q0 + c) * 64 + g * 8);
  bf16x8 qa1 = *(const bf16x8*)(Qp + (size_t)(q0 + c) * 64 + 32 + g * 8);

  // per-row bias scalars for rows q = q0 + 4g + r
  float pbq[4], cbq[4];
#pragma unroll
  for (int r = 0; r < 4; ++r) {
    pbq[r] = pbw[bh * 1024 + q0 + 4 * g + r];
    cbq[r] = cbw[bh * 1024 + q0 + 4 * g + r];
  }
  // mask row base offsets (elements) for rows 4g+r
  const int qoff = (b * 1024 + q0 + 4 * g) * 1024;
  const int* padrow = padm + b * 1024;

  f32x4 oacc[4] = {{0,0,0,0},{0,0,0,0},{0,0,0,0},{0,0,0,0}};
  float mrow[4] = {-1e30f,-1e30f,-1e30f,-1e30f};
  float lrow[4] = {0.f,0.f,0.f,0.f};

  for (int kt = 0; kt < 8; ++kt) {
    const int k0 = kt * 128;
    __syncthreads();                 // all waves done reading Kt/Vt of prev tile
    // ---- stage K tile: 128 rows x 64 d  (1024 x 16B chunks)
#pragma unroll
    for (int i = 0; i < 4; ++i) {
      int idx = t + i * 256;
      int r = idx >> 3, cc = idx & 7;
      *(uint4*)&Kt[r][cc * 8] = *(const uint4*)(Kp + (size_t)(k0 + r) * 64 + cc * 8);
    }
    // ---- stage V^T tile: 64 rows(d) x 128 keys
#pragma unroll
    for (int i = 0; i < 4; ++i) {
      int idx = t + i * 256;
      int r = idx >> 4, cc = idx & 15;
      *(uint4*)&Vt[r][cc * 8] = *(const uint4*)(Vg + (size_t)r * 1024 + k0 + cc * 8);
    }
    __syncthreads();
    // ---- QK^T: 8 column tiles of 16 keys
    f32x4 sacc[8];
#pragma unroll
    for (int nt = 0; nt < 8; ++nt) {
      f32x4 z = {0.f,0.f,0.f,0.f};
      bf16x8 k0f = *(const bf16x8*)&Kt[nt * 16 + c][g * 8];
      bf16x8 k1f = *(const bf16x8*)&Kt[nt * 16 + c][32 + g * 8];
      z = __builtin_amdgcn_mfma_f32_16x16x32_bf16(qa0, k0f, z, 0, 0, 0);
      z = __builtin_amdgcn_mfma_f32_16x16x32_bf16(qa1, k1f, z, 0, 0, 0);
      sacc[nt] = z;
    }
    // ---- pad mask for this lane's columns
    int padv[8];
#pragma unroll
    for (int nt = 0; nt < 8; ++nt) padv[nt] = padrow[k0 + nt * 16 + c];
    // ---- bias + mask + online softmax (C-layout: lane = col c, rows 4g+r)
    float al[4];
#pragma unroll
    for (int r = 0; r < 4; ++r) {
      const int ro = qoff + r * 1024;
      float sv[8];
      float mx = -1e30f;
#pragma unroll
      for (int nt = 0; nt < 8; ++nt) {
        int kg = k0 + nt * 16 + c;
        float pmv  = pm[ro + kg];
        float pmtv = __bfloat162float(pmT[ro + kg]);
        int msk = hid[ro + kg] | padv[nt];
        float s = sacc[nt][r] * 0.125f + pmtv * pbq[r] + pmv * cbq[r];
        s = msk ? -1e30f : s;
        sv[nt] = s;
        mx = fmaxf(mx, s);
      }
#pragma unroll
      for (int off = 8; off; off >>= 1) mx = fmaxf(mx, __shfl_xor(mx, off));
      float newm = fmaxf(mrow[r], mx);
      al[r] = __expf(mrow[r] - newm);
      float ps = 0.f;
#pragma unroll
      for (int nt = 0; nt < 8; ++nt) {
        float p = (sv[nt] <= -1e29f) ? 0.f : __expf(sv[nt] - newm);
        ps += p;
        Ps[wave][4 * g + r][nt * 16 + c] = __float2bfloat16(p);
      }
#pragma unroll
      for (int off = 8; off; off >>= 1) ps += __shfl_xor(ps, off);
      lrow[r] = lrow[r] * al[r] + ps;
      mrow[r] = newm;
    }
    // ---- alpha for this lane's PV column q = c (lives in quad c>>2, slot c&3)
    {
      int srcl = (c >> 2) * 16;
      float a0 = __shfl(al[0], srcl), a1 = __shfl(al[1], srcl);
      float a2 = __shfl(al[2], srcl), a3 = __shfl(al[3], srcl);
      int rr = c & 3;
      float aq = rr == 0 ? a0 : rr == 1 ? a1 : rr == 2 ? a2 : a3;
#pragma unroll
      for (int dt = 0; dt < 4; ++dt) {
        oacc[dt][0] *= aq; oacc[dt][1] *= aq;
        oacc[dt][2] *= aq; oacc[dt][3] *= aq;
      }
    }
    // ---- PV: O^T[d][q] += sum_k V^T[d][k] * P[q][k]   (NT form, A=Vt, B=Ps)
#pragma unroll
    for (int dt = 0; dt < 4; ++dt) {
#pragma unroll
      for (int kc = 0; kc < 4; ++kc) {
        bf16x8 vf = *(const bf16x8*)&Vt[dt * 16 + c][kc * 32 + g * 8];
        bf16x8 pf = *(const bf16x8*)&Ps[wave][c][kc * 32 + g * 8];
        oacc[dt] = __builtin_amdgcn_mfma_f32_16x16x32_bf16(vf, pf, oacc[dt], 0, 0, 0);
      }
    }
  }
  // ---- epilogue: lane holds O[q = q0+c][d = dt*16 + 4g + reg]
  float lq;
  {
    int srcl = (c >> 2) * 16;
    float l0 = __shfl(lrow[0], srcl), l1 = __shfl(lrow[1], srcl);
    float l2 = __shfl(lrow[2], srcl), l3 = __shfl(lrow[3], srcl);
    int rr = c & 3;
    lq = rr == 0 ? l0 : rr == 1 ? l1 : rr == 2 ? l2 : l3;
  }
  const float inv = (lq > 0.f) ? 1.f / lq : 0.f;
  const int qg = q0 + c;
#pragma unroll
  for (int dt = 0; dt < 4; ++dt)
#pragma unroll
    for (int rg = 0; rg < 4; ++rg) {
      int d = dt * 16 + 4 * g + rg;
      ctxo[((size_t)qg * 4 + b) * 512 + h * 64 + d] =
          __float2bfloat16(oacc[dt][rg] * inv);
    }
}

// ---------------------------------------------------------------------------
// out = LayerNorm(a + rsd) * g + be   (row = 512 elems, wave per row)
// ---------------------------------------------------------------------------
template<typename TA, typename TR, typename TO>
__global__ __launch_bounds__(256)
void ln_res(const TA* __restrict__ a, const TR* __restrict__ rsd,
            const float* __restrict__ g, const float* __restrict__ be,
            TO* __restrict__ out)
{
  const int wave = threadIdx.x >> 6, lane = threadIdx.x & 63;
  const int m = blockIdx.x * 4 + wave;
  const size_t base = (size_t)m * 512 + lane * 8;
  float va[8], vb[8];
  load8(a + base, va);
  load8(rsd + base, vb);
  float v[8], s = 0.f;
#pragma unroll
  for (int j = 0; j < 8; ++j) { v[j] = va[j] + vb[j]; s += v[j]; }
#pragma unroll
  for (int off = 32; off; off >>= 1) s += __shfl_xor(s, off);
  const float mean = s * (1.f / 512.f);
  float q = 0.f;
#pragma unroll
  for (int j = 0; j < 8; ++j) { float d = v[j] - mean; q += d * d; }
#pragma unroll
  for (int off = 32; off; off >>= 1) q += __shfl_xor(q, off);
  const float rs = rsqrtf(q * (1.f / 512.f) + 1e-5f);
  float gv[8], bv[8];
  load8(g + lane * 8, gv);
  load8(be + lane * 8, bv);
#pragma unroll
  for (int j = 0; j < 8; ++j)
    store1(out + base + j, (v[j] - mean) * rs * gv[j] + bv[j]);
}

// ---------------------------------------------------------------------------
extern "C" void kernel_launch(void* const* d_in, const int* in_sizes, int n_in,
                              void* d_out, int out_size, void* d_ws, size_t ws_size,
                              hipStream_t stream)
{
  (void)in_sizes; (void)n_in; (void)out_size; (void)ws_size;
  const float* x    = (const float*)d_in[0];
  const float* pm   = (const float*)d_in[1];
  const int*   hid  = (const int*)d_in[2];
  const int*   padm = (const int*)d_in[3];
  const float* Wp   = (const float*)d_in[4];
  const float* bp   = (const float*)d_in[5];
  const float* Wc   = (const float*)d_in[6];
  const float* bc   = (const float*)d_in[7];
  const float* Wqkv = (const float*)d_in[8];
  const float* bqkv = (const float*)d_in[9];
  const float* Wo   = (const float*)d_in[10];
  const float* bo   = (const float*)d_in[11];
  const float* W1   = (const float*)d_in[12];
  const float* b1   = (const float*)d_in[13];
  const float* W2   = (const float*)d_in[14];
  const float* b2   = (const float*)d_in[15];
  const float* g1   = (const float*)d_in[16];
  const float* be1  = (const float*)d_in[17];
  const float* g2   = (const float*)d_in[18];
  const float* be2  = (const float*)d_in[19];

  // Workspace layout (max offset 33,816,576 B ~= 32.25 MiB; aliases noted)
  char* ws = (char*)d_ws;
  bf16*  qkvb  = (bf16*) (ws);               // 12,582,912 B: Q,K [w][b][h][n][64]; V [b][h][d][n]
  float* pbo   = (float*)(ws + 12582912);    //    131,072 B: [B][H][N] f32
  float* cbo   = (float*)(ws + 12713984);    //    131,072 B
  bf16*  pmT   = (bf16*) (ws + 12845056);    //  8,388,608 B: [B][N][N] bf16
  bf16*  ctx   = (bf16*) (ws + 21233664);    //  4,194,304 B: [M][512]
  bf16*  attno = (bf16*) (ws + 25427968);    //  4,194,304 B
  bf16*  y     = (bf16*) (ws + 29622272);    //  4,194,304 B  (ends 33,816,576)
  bf16*  ff1   = (bf16*) (ws);               // 16,777,216 B: aliases qkv+pb+cb+pmT-head (dead after attn)
  bf16*  ff2   = (bf16*) (ws + 21233664);    //  4,194,304 B: aliases ctx (dead after Wo gemm)

  transpose_pm<<<dim3(16, 16, 4), 256, 0, stream>>>(pm, pmT);
  pbcb_kernel<<<1024, 256, 0, stream>>>(x, Wp, bp, Wc, bc, pbo, cbo);
  gemm_bt<2, float><<<dim3(24, 64), 256, 0, stream>>>(x, Wqkv, bqkv, qkvb, 4096, 1536, 512);
  attn_mfma<<<dim3(16, 8, 4), 256, 0, stream>>>(qkvb, pbo, cbo, pm, pmT, hid, padm, ctx);
  gemm_bt<0, bf16><<<dim3(8, 64), 256, 0, stream>>>(ctx, Wo, bo, attno, 4096, 512, 512);
  ln_res<float, bf16, bf16><<<1024, 256, 0, stream>>>(x, attno, g1, be1, y);
  gemm_bt<1, bf16><<<dim3(32, 64), 256, 0, stream>>>(y, W1, b1, ff1, 4096, 2048, 512);
  gemm_bt<0, bf16><<<dim3(8, 64), 256, 0, stream>>>(ff1, W2, b2, ff2, 4096, 512, 2048);
  ln_res<bf16, bf16, float><<<1024, 256, 0, stream>>>(y, ff2, g2, be2, (float*)d_out);
}

// Round 5
// 301.469 us; speedup vs baseline: 3.2879x; 1.3508x over previous
//
#include <hip/hip_runtime.h>
#include <hip/hip_bf16.h>
#include <stdint.h>

using bf16 = __hip_bfloat16;

typedef __bf16 bf16x8 __attribute__((ext_vector_type(8)));
typedef float  f32x4  __attribute__((ext_vector_type(4)));

__device__ __forceinline__ float bflo(uint32_t u) { return __uint_as_float(u << 16); }
__device__ __forceinline__ float bfhi(uint32_t u) { return __uint_as_float(u & 0xffff0000u); }

__device__ __forceinline__ void load8(const bf16* p, float* f) {
  uint4 u = *(const uint4*)p;
  f[0] = bflo(u.x); f[1] = bfhi(u.x);
  f[2] = bflo(u.y); f[3] = bfhi(u.y);
  f[4] = bflo(u.z); f[5] = bfhi(u.z);
  f[6] = bflo(u.w); f[7] = bfhi(u.w);
}
__device__ __forceinline__ void load8(const float* p, float* f) {
  float4 a = *(const float4*)p, b = *(const float4*)(p + 4);
  f[0] = a.x; f[1] = a.y; f[2] = a.z; f[3] = a.w;
  f[4] = b.x; f[5] = b.y; f[6] = b.z; f[7] = b.w;
}
__device__ __forceinline__ void store1(float* o, float v) { *o = v; }
__device__ __forceinline__ void store1(bf16* o, float v) { *o = __float2bfloat16(v); }
__device__ __forceinline__ uint32_t bfbits(float x) {
  bf16 v = __float2bfloat16(x);
  return (uint32_t)*(uint16_t*)&v;
}

// ---- async global->LDS, 16B per lane; lds base must be wave-uniform -------
typedef const uint32_t __attribute__((address_space(1)))* gp_t;
typedef uint32_t __attribute__((address_space(3)))* lp_t;
__device__ __forceinline__ void gload16(const void* g, void* l) {
  __builtin_amdgcn_global_load_lds((gp_t)g, (lp_t)l, 16, 0, 0);
}

// ---------------------------------------------------------------------------
// f32 -> bf16 bulk convert of x, Wqkv, Wo, W1, W2 (fixed sizes, one launch)
// ---------------------------------------------------------------------------
__global__ __launch_bounds__(256)
void cvt5(const float* __restrict__ s0, const float* __restrict__ s1,
          const float* __restrict__ s2, const float* __restrict__ s3,
          const float* __restrict__ s4, bf16* __restrict__ d0,
          bf16* __restrict__ d1, bf16* __restrict__ d2,
          bf16* __restrict__ d3, bf16* __restrict__ d4)
{
  size_t j = ((size_t)blockIdx.x * 256 + threadIdx.x) * 8;
  const float* s; bf16* o; size_t off;
  if      (j < 2097152) { s = s0; o = d0; off = j; }
  else if (j < 2883584) { s = s1; o = d1; off = j - 2097152; }
  else if (j < 3145728) { s = s2; o = d2; off = j - 2883584; }
  else if (j < 4194304) { s = s3; o = d3; off = j - 3145728; }
  else                  { s = s4; o = d4; off = j - 4194304; }
  float f[8];
  load8(s + off, f);
  uint4 u;
  u.x = (bfbits(f[1]) << 16) | bfbits(f[0]);
  u.y = (bfbits(f[3]) << 16) | bfbits(f[2]);
  u.z = (bfbits(f[5]) << 16) | bfbits(f[4]);
  u.w = (bfbits(f[7]) << 16) | bfbits(f[6]);
  *(uint4*)(o + off) = u;
}

// ---------------------------------------------------------------------------
// Packed attention mask: out[b][q][k0 + (k&15)*8 + (k>>4)&7] =
//   hid|pad ? 0xFFFFFFFF : (bf16(pm[b,k,q])<<16 | bf16(pm[b,q,k]))
// Permutation makes attn's per-lane 8 tile-columns contiguous (2x uint4).
// ---------------------------------------------------------------------------
__global__ __launch_bounds__(256)
void mask_pack(const float* __restrict__ pm, const int* __restrict__ hid,
               const int* __restrict__ padm, uint32_t* __restrict__ out)
{
  __shared__ float tileT[128][65];   // [k-local][q-local]
  const int b = blockIdx.z, q0 = blockIdx.y * 64, k0 = blockIdx.x * 128;
  const int t = threadIdx.x;
  const size_t pb = (size_t)b << 20;
#pragma unroll
  for (int i = 0; i < 32; ++i) {     // stage pm[b][k0+r][q0+c]
    int idx = t + i * 256;
    int r = idx >> 6, c = idx & 63;
    tileT[r][c] = pm[pb + (size_t)(k0 + r) * 1024 + q0 + c];
  }
  __syncthreads();
#pragma unroll
  for (int i = 0; i < 32; ++i) {
    int idx = t + i * 256;           // 64 q x 128 pos
    int q = idx >> 7, pos = idx & 127;
    int k = (pos & 7) * 16 + (pos >> 3);
    size_t src = pb + (size_t)(q0 + q) * 1024 + k0 + k;
    int msk = hid[src] | padm[b * 1024 + k0 + k];
    uint32_t u = 0xFFFFFFFFu;
    if (!msk) u = (bfbits(tileT[k][q]) << 16) | bfbits(pm[src]);
    out[pb + (size_t)(q0 + q) * 1024 + k0 + pos] = u;
  }
}

// ---------------------------------------------------------------------------
// GEMM: C[M,Nout] = A[M,K] * W[Nout,K]^T + bias   (bf16 in, f32 accum)
// 128 x BN tile, BK=64, global_load_lds(16B) staging, 4 waves.
// MODE 0: store. MODE 1: relu+store.
// MODE 2: QKV scatter: Q,K -> [which][b][h][n][d]; V -> transposed [b][h][d][n]
// ---------------------------------------------------------------------------
template<int MODE, int BN>
__global__ __launch_bounds__(256)
void gemm_bt(const bf16* __restrict__ A, const bf16* __restrict__ W,
             const float* __restrict__ bias, bf16* __restrict__ outb,
             int M, int Nout, int K)
{
  constexpr int NT = BN / 32;        // 16-col tiles per wave
  __shared__ bf16 As[128 * 64];
  __shared__ bf16 Bs[BN * 64];
  const int t = threadIdx.x, lane = t & 63, wave = t >> 6;
  const int m0 = blockIdx.y * 128, n0 = blockIdx.x * BN;
  const int wr = wave >> 1, wc = wave & 1;
  const int frow = lane & 15, ksel = (lane >> 4) * 8;
  f32x4 acc[4 * NT] = {};
  const bf16* Ab = A + (size_t)m0 * K;
  const bf16* Wb = W + (size_t)n0 * K;

  for (int k0 = 0; k0 < K; k0 += 64) {
    __syncthreads();
#pragma unroll
    for (int i = 0; i < 4; ++i) {    // A: 1024 x 16B chunks
      int ib = i * 256 + wave * 64;
      int idx = ib + lane;
      gload16(Ab + (size_t)(idx >> 3) * K + k0 + (idx & 7) * 8, As + ib * 8);
    }
#pragma unroll
    for (int i = 0; i < BN / 32; ++i) {  // B: BN*8 chunks
      int ib = i * 256 + wave * 64;
      int idx = ib + lane;
      gload16(Wb + (size_t)(idx >> 3) * K + k0 + (idx & 7) * 8, Bs + ib * 8);
    }
    __syncthreads();                 // drains vmcnt -> LDS valid
#pragma unroll
    for (int kk = 0; kk < 64; kk += 32) {
      bf16x8 af[4], bf_[NT];
#pragma unroll
      for (int mt = 0; mt < 4; ++mt)
        af[mt] = *(const bf16x8*)(As + (wr * 64 + mt * 16 + frow) * 64 + kk + ksel);
#pragma unroll
      for (int nt = 0; nt < NT; ++nt)
        bf_[nt] = *(const bf16x8*)(Bs + (wc * (BN / 2) + nt * 16 + frow) * 64 + kk + ksel);
#pragma unroll
      for (int mt = 0; mt < 4; ++mt)
#pragma unroll
        for (int nt = 0; nt < NT; ++nt)
          acc[mt * NT + nt] = __builtin_amdgcn_mfma_f32_16x16x32_bf16(
              af[mt], bf_[nt], acc[mt * NT + nt], 0, 0, 0);
    }
  }
  const int rb = (lane >> 4) * 4, cb = lane & 15;
#pragma unroll
  for (int mt = 0; mt < 4; ++mt)
#pragma unroll
    for (int nt = 0; nt < NT; ++nt) {
      f32x4 a = acc[mt * NT + nt];
#pragma unroll
      for (int r = 0; r < 4; ++r) {
        int row = m0 + wr * 64 + mt * 16 + rb + r;
        int col = n0 + wc * (BN / 2) + nt * 16 + cb;
        float v = a[r] + bias[col];
        if (MODE == 1) v = fmaxf(v, 0.f);
        if (MODE == 2) {
          int which = col >> 9, hh = (col >> 6) & 7, d = col & 63;
          int n = row >> 2, b = row & 3;
          size_t idx;
          if (which == 2)   // V transposed: [b][h][d][n]
            idx = (((size_t)(64 + b * 8 + hh)) << 16) + (size_t)d * 1024 + n;
          else              // Q,K: [which][b][h][n][d]
            idx = (((size_t)(which * 32 + b * 8 + hh)) << 16) + (size_t)n * 64 + d;
          outb[idx] = __float2bfloat16(v);
        } else {
          outb[(size_t)row * Nout + col] = __float2bfloat16(v);
        }
      }
    }
}

// ---------------------------------------------------------------------------
// parent/child bias projections: pb[b,h,n] = x[n,b,:].Wp[h,:] + bp[h]
// ---------------------------------------------------------------------------
__global__ __launch_bounds__(256)
void pbcb_kernel(const float* __restrict__ x, const float* __restrict__ Wp,
                 const float* __restrict__ bp, const float* __restrict__ Wc,
                 const float* __restrict__ bc, float* __restrict__ pbo,
                 float* __restrict__ cbo)
{
  const int wave = threadIdx.x >> 6, lane = threadIdx.x & 63;
  const int m = blockIdx.x * 4 + wave;     // m = n*4 + b
  float xv[8];
  load8(x + (size_t)m * 512 + lane * 8, xv);
  const int n = m >> 2, b = m & 3;
#pragma unroll
  for (int hh = 0; hh < 8; ++hh) {
    float wp[8], wc[8];
    load8(Wp + (size_t)hh * 512 + lane * 8, wp);
    load8(Wc + (size_t)hh * 512 + lane * 8, wc);
    float ap = 0.f, ac = 0.f;
#pragma unroll
    for (int j = 0; j < 8; ++j) { ap += xv[j] * wp[j]; ac += xv[j] * wc[j]; }
#pragma unroll
    for (int off = 32; off; off >>= 1) {
      ap += __shfl_xor(ap, off);
      ac += __shfl_xor(ac, off);
    }
    if (lane == 0) {
      pbo[((size_t)b * 8 + hh) * 1024 + n] = ap + bp[hh];
      cbo[((size_t)b * 8 + hh) * 1024 + n] = ac + bc[hh];
    }
  }
}

// ---------------------------------------------------------------------------
// MFMA flash attention. Block = 64 q-rows of one (b,h); 4 waves x 16 q-rows.
// K-tile = 128 keys. QK^T NT-form MFMA; PV as O^T = V^T*P. Packed mask:
// one uint32 per (q,k) = (bf16 pmT << 16)|bf16 pm, 0xFFFFFFFF = masked,
// permuted so lane c reads its 8 tile-columns as 2 uint4 loads.
// ---------------------------------------------------------------------------
__global__ __launch_bounds__(256, 3)
void attn_mfma(const bf16* __restrict__ qkv, const float* __restrict__ pbw,
               const float* __restrict__ cbw, const uint32_t* __restrict__ mpk,
               bf16* __restrict__ ctxo)
{
  __shared__ bf16 Kt[128][72];
  __shared__ bf16 Vt[64][136];
  __shared__ bf16 Ps[4][16][136];
  const int t = threadIdx.x, lane = t & 63, wave = t >> 6;
  const int g = lane >> 4, c = lane & 15;
  const int h = blockIdx.y, b = blockIdx.z;
  const int q0 = blockIdx.x * 64 + wave * 16;
  const size_t bh = (size_t)b * 8 + h;
  const bf16* Qp = qkv + (bh << 16);
  const bf16* Kp = qkv + ((32 + bh) << 16);
  const bf16* Vg = qkv + ((64 + bh) << 16);     // [64 d][1024 n]

  bf16x8 qa0 = *(const bf16x8*)(Qp + (size_t)(q0 + c) * 64 + g * 8);
  bf16x8 qa1 = *(const bf16x8*)(Qp + (size_t)(q0 + c) * 64 + 32 + g * 8);

  float pbq[4], cbq[4];
#pragma unroll
  for (int r = 0; r < 4; ++r) {
    pbq[r] = pbw[bh * 1024 + q0 + 4 * g + r];
    cbq[r] = cbw[bh * 1024 + q0 + 4 * g + r];
  }
  const uint32_t* mbase = mpk + (((size_t)b * 1024 + q0 + 4 * g) << 10) + c * 8;

  f32x4 oacc[4] = {{0,0,0,0},{0,0,0,0},{0,0,0,0},{0,0,0,0}};
  float mrow[4] = {-1e30f,-1e30f,-1e30f,-1e30f};
  float lrow[4] = {0.f,0.f,0.f,0.f};

  for (int kt = 0; kt < 8; ++kt) {
    const int k0 = kt * 128;
    __syncthreads();
#pragma unroll
    for (int i = 0; i < 4; ++i) {    // K tile
      int idx = t + i * 256;
      int r = idx >> 3, cc = idx & 7;
      *(uint4*)&Kt[r][cc * 8] = *(const uint4*)(Kp + (size_t)(k0 + r) * 64 + cc * 8);
    }
#pragma unroll
    for (int i = 0; i < 4; ++i) {    // V^T tile
      int idx = t + i * 256;
      int r = idx >> 4, cc = idx & 15;
      *(uint4*)&Vt[r][cc * 8] = *(const uint4*)(Vg + (size_t)r * 1024 + k0 + cc * 8);
    }
    __syncthreads();
    // ---- QK^T
    f32x4 sacc[8];
#pragma unroll
    for (int nt = 0; nt < 8; ++nt) {
      f32x4 z = {0.f,0.f,0.f,0.f};
      bf16x8 k0f = *(const bf16x8*)&Kt[nt * 16 + c][g * 8];
      bf16x8 k1f = *(const bf16x8*)&Kt[nt * 16 + c][32 + g * 8];
      z = __builtin_amdgcn_mfma_f32_16x16x32_bf16(qa0, k0f, z, 0, 0, 0);
      z = __builtin_amdgcn_mfma_f32_16x16x32_bf16(qa1, k1f, z, 0, 0, 0);
      sacc[nt] = z;
    }
    // ---- bias + mask + online softmax
    float al[4];
#pragma unroll
    for (int r = 0; r < 4; ++r) {
      const uint32_t* mp = mbase + ((size_t)r << 10) + k0;
      uint4 u0 = *(const uint4*)mp;
      uint4 u1 = *(const uint4*)(mp + 4);
      uint32_t uu[8] = {u0.x, u0.y, u0.z, u0.w, u1.x, u1.y, u1.z, u1.w};
      float sv[8];
      float mx = -1e30f;
#pragma unroll
      for (int nt = 0; nt < 8; ++nt) {
        float s = sacc[nt][r] * 0.125f + bfhi(uu[nt]) * pbq[r] + bflo(uu[nt]) * cbq[r];
        s = (uu[nt] == 0xFFFFFFFFu) ? -1e30f : s;
        sv[nt] = s;
        mx = fmaxf(mx, s);
      }
#pragma unroll
      for (int off = 8; off; off >>= 1) mx = fmaxf(mx, __shfl_xor(mx, off));
      float newm = fmaxf(mrow[r], mx);
      al[r] = __expf(mrow[r] - newm);
      float ps = 0.f;
#pragma unroll
      for (int nt = 0; nt < 8; ++nt) {
        float p = (sv[nt] <= -1e29f) ? 0.f : __expf(sv[nt] - newm);
        ps += p;
        Ps[wave][4 * g + r][nt * 16 + c] = __float2bfloat16(p);
      }
#pragma unroll
      for (int off = 8; off; off >>= 1) ps += __shfl_xor(ps, off);
      lrow[r] = lrow[r] * al[r] + ps;
      mrow[r] = newm;
    }
    // ---- alpha for this lane's PV column q = c
    {
      int srcl = (c >> 2) * 16;
      float a0 = __shfl(al[0], srcl), a1 = __shfl(al[1], srcl);
      float a2 = __shfl(al[2], srcl), a3 = __shfl(al[3], srcl);
      int rr = c & 3;
      float aq = rr == 0 ? a0 : rr == 1 ? a1 : rr == 2 ? a2 : a3;
#pragma unroll
      for (int dt = 0; dt < 4; ++dt) {
        oacc[dt][0] *= aq; oacc[dt][1] *= aq;
        oacc[dt][2] *= aq; oacc[dt][3] *= aq;
      }
    }
    // ---- PV: O^T[d][q] += sum_k V^T[d][k] * P[q][k]
#pragma unroll
    for (int dt = 0; dt < 4; ++dt) {
#pragma unroll
      for (int kc = 0; kc < 4; ++kc) {
        bf16x8 vf = *(const bf16x8*)&Vt[dt * 16 + c][kc * 32 + g * 8];
        bf16x8 pf = *(const bf16x8*)&Ps[wave][c][kc * 32 + g * 8];
        oacc[dt] = __builtin_amdgcn_mfma_f32_16x16x32_bf16(vf, pf, oacc[dt], 0, 0, 0);
      }
    }
  }
  float lq;
  {
    int srcl = (c >> 2) * 16;
    float l0 = __shfl(lrow[0], srcl), l1 = __shfl(lrow[1], srcl);
    float l2 = __shfl(lrow[2], srcl), l3 = __shfl(lrow[3], srcl);
    int rr = c & 3;
    lq = rr == 0 ? l0 : rr == 1 ? l1 : rr == 2 ? l2 : l3;
  }
  const float inv = (lq > 0.f) ? 1.f / lq : 0.f;
  const int qg = q0 + c;
#pragma unroll
  for (int dt = 0; dt < 4; ++dt)
#pragma unroll
    for (int rg = 0; rg < 4; ++rg) {
      int d = dt * 16 + 4 * g + rg;
      ctxo[((size_t)qg * 4 + b) * 512 + h * 64 + d] =
          __float2bfloat16(oacc[dt][rg] * inv);
    }
}

// ---------------------------------------------------------------------------
// out = LayerNorm(a + rsd) * g + be   (row = 512 elems, wave per row)
// ---------------------------------------------------------------------------
template<typename TA, typename TR, typename TO>
__global__ __launch_bounds__(256)
void ln_res(const TA* __restrict__ a, const TR* __restrict__ rsd,
            const float* __restrict__ g, const float* __restrict__ be,
            TO* __restrict__ out)
{
  const int wave = threadIdx.x >> 6, lane = threadIdx.x & 63;
  const int m = blockIdx.x * 4 + wave;
  const size_t base = (size_t)m * 512 + lane * 8;
  float va[8], vb[8];
  load8(a + base, va);
  load8(rsd + base, vb);
  float v[8], s = 0.f;
#pragma unroll
  for (int j = 0; j < 8; ++j) { v[j] = va[j] + vb[j]; s += v[j]; }
#pragma unroll
  for (int off = 32; off; off >>= 1) s += __shfl_xor(s, off);
  const float mean = s * (1.f / 512.f);
  float q = 0.f;
#pragma unroll
  for (int j = 0; j < 8; ++j) { float d = v[j] - mean; q += d * d; }
#pragma unroll
  for (int off = 32; off; off >>= 1) q += __shfl_xor(q, off);
  const float rs = rsqrtf(q * (1.f / 512.f) + 1e-5f);
  float gv[8], bv[8];
  load8(g + lane * 8, gv);
  load8(be + lane * 8, bv);
#pragma unroll
  for (int j = 0; j < 8; ++j)
    store1(out + base + j, (v[j] - mean) * rs * gv[j] + bv[j]);
}

// ---------------------------------------------------------------------------
extern "C" void kernel_launch(void* const* d_in, const int* in_sizes, int n_in,
                              void* d_out, int out_size, void* d_ws, size_t ws_size,
                              hipStream_t stream)
{
  (void)in_sizes; (void)n_in; (void)out_size; (void)ws_size;
  const float* x    = (const float*)d_in[0];
  const float* pm   = (const float*)d_in[1];
  const int*   hid  = (const int*)d_in[2];
  const int*   padm = (const int*)d_in[3];
  const float* Wp   = (const float*)d_in[4];
  const float* bp   = (const float*)d_in[5];
  const float* Wc   = (const float*)d_in[6];
  const float* bc   = (const float*)d_in[7];
  const float* Wqkv = (const float*)d_in[8];
  const float* bqkv = (const float*)d_in[9];
  const float* Wo   = (const float*)d_in[10];
  const float* bo   = (const float*)d_in[11];
  const float* W1   = (const float*)d_in[12];
  const float* b1   = (const float*)d_in[13];
  const float* W2   = (const float*)d_in[14];
  const float* b2   = (const float*)d_in[15];
  const float* g1   = (const float*)d_in[16];
  const float* be1  = (const float*)d_in[17];
  const float* g2   = (const float*)d_in[18];
  const float* be2  = (const float*)d_in[19];

  // Workspace layout (max 52,690,944 B ~= 50.25 MiB; aliases noted)
  char* ws = (char*)d_ws;
  bf16*     qkvb  = (bf16*)    (ws);               // 12,582,912 B
  float*    pbo   = (float*)   (ws + 12582912);    //    131,072 B
  float*    cbo   = (float*)   (ws + 12713984);    //    131,072 B
  uint32_t* mpk   = (uint32_t*)(ws + 12845056);    // 16,777,216 B packed mask
  bf16*     ctx   = (bf16*)    (ws + 29622272);    //  4,194,304 B
  bf16*     attno = (bf16*)    (ws + 33816576);    //  4,194,304 B
  bf16*     y     = (bf16*)    (ws + 38010880);    //  4,194,304 B
  bf16*     xb    = (bf16*)    (ws + 42205184);    //  4,194,304 B x as bf16
  bf16*     wqkvb = (bf16*)    (ws + 46399488);    //  1,572,864 B
  bf16*     wob   = (bf16*)    (ws + 47972352);    //    524,288 B
  bf16*     w1b   = (bf16*)    (ws + 48496640);    //  2,097,152 B
  bf16*     w2b   = (bf16*)    (ws + 50593792);    //  2,097,152 B (end 52,690,944)
  bf16*     ff1   = (bf16*)    (ws);               // 16,777,216 B alias qkvb/pbo/cbo/mpk-head
  bf16*     ff2   = (bf16*)    (ws + 29622272);    //  4,194,304 B alias ctx

  cvt5<<<2560, 256, 0, stream>>>(x, Wqkv, Wo, W1, W2, xb, wqkvb, wob, w1b, w2b);
  mask_pack<<<dim3(8, 16, 4), 256, 0, stream>>>(pm, hid, padm, mpk);
  pbcb_kernel<<<1024, 256, 0, stream>>>(x, Wp, bp, Wc, bc, pbo, cbo);
  gemm_bt<2, 128><<<dim3(12, 32), 256, 0, stream>>>(xb, wqkvb, bqkv, qkvb, 4096, 1536, 512);
  attn_mfma<<<dim3(16, 8, 4), 256, 0, stream>>>(qkvb, pbo, cbo, mpk, ctx);
  gemm_bt<0, 64><<<dim3(8, 32), 256, 0, stream>>>(ctx, wob, bo, attno, 4096, 512, 512);
  ln_res<float, bf16, bf16><<<1024, 256, 0, stream>>>(x, attno, g1, be1, y);
  gemm_bt<1, 128><<<dim3(16, 32), 256, 0, stream>>>(y, w1b, b1, ff1, 4096, 2048, 512);
  gemm_bt<0, 64><<<dim3(8, 32), 256, 0, stream>>>(ff1, w2b, b2, ff2, 4096, 512, 2048);
  ln_res<bf16, bf16, float><<<1024, 256, 0, stream>>>(y, ff2, g2, be2, (float*)d_out);
}

// Round 6
// 278.763 us; speedup vs baseline: 3.5557x; 1.0815x over previous
//
#include <hip/hip_runtime.h>
#include <hip/hip_bf16.h>
#include <stdint.h>

using bf16 = __hip_bfloat16;

typedef __bf16 bf16x8 __attribute__((ext_vector_type(8)));
typedef float  f32x4  __attribute__((ext_vector_type(4)));

__device__ __forceinline__ float bflo(uint32_t u) { return __uint_as_float(u << 16); }
__device__ __forceinline__ float bfhi(uint32_t u) { return __uint_as_float(u & 0xffff0000u); }

__device__ __forceinline__ void load8(const bf16* p, float* f) {
  uint4 u = *(const uint4*)p;
  f[0] = bflo(u.x); f[1] = bfhi(u.x);
  f[2] = bflo(u.y); f[3] = bfhi(u.y);
  f[4] = bflo(u.z); f[5] = bfhi(u.z);
  f[6] = bflo(u.w); f[7] = bfhi(u.w);
}
__device__ __forceinline__ void load8(const float* p, float* f) {
  float4 a = *(const float4*)p, b = *(const float4*)(p + 4);
  f[0] = a.x; f[1] = a.y; f[2] = a.z; f[3] = a.w;
  f[4] = b.x; f[5] = b.y; f[6] = b.z; f[7] = b.w;
}
__device__ __forceinline__ void store1(float* o, float v) { *o = v; }
__device__ __forceinline__ void store1(bf16* o, float v) { *o = __float2bfloat16(v); }
__device__ __forceinline__ uint32_t bfbits(float x) {
  bf16 v = __float2bfloat16(x);
  return (uint32_t)*(uint16_t*)&v;
}

// ---- async global->LDS, 16B per lane; lds base must be wave-uniform -------
typedef const uint32_t __attribute__((address_space(1)))* gp_t;
typedef uint32_t __attribute__((address_space(3)))* lp_t;
__device__ __forceinline__ void gload16(const void* g, void* l) {
  __builtin_amdgcn_global_load_lds((gp_t)g, (lp_t)l, 16, 0, 0);
}

// ---------------------------------------------------------------------------
// f32 -> bf16 bulk convert of x, Wqkv, Wo, W1, W2 (fixed sizes, one launch)
// ---------------------------------------------------------------------------
__global__ __launch_bounds__(256)
void cvt5(const float* __restrict__ s0, const float* __restrict__ s1,
          const float* __restrict__ s2, const float* __restrict__ s3,
          const float* __restrict__ s4, bf16* __restrict__ d0,
          bf16* __restrict__ d1, bf16* __restrict__ d2,
          bf16* __restrict__ d3, bf16* __restrict__ d4)
{
  size_t j = ((size_t)blockIdx.x * 256 + threadIdx.x) * 8;
  const float* s; bf16* o; size_t off;
  if      (j < 2097152) { s = s0; o = d0; off = j; }
  else if (j < 2883584) { s = s1; o = d1; off = j - 2097152; }
  else if (j < 3145728) { s = s2; o = d2; off = j - 2883584; }
  else if (j < 4194304) { s = s3; o = d3; off = j - 3145728; }
  else                  { s = s4; o = d4; off = j - 4194304; }
  float f[8];
  load8(s + off, f);
  uint4 u;
  u.x = (bfbits(f[1]) << 16) | bfbits(f[0]);
  u.y = (bfbits(f[3]) << 16) | bfbits(f[2]);
  u.z = (bfbits(f[5]) << 16) | bfbits(f[4]);
  u.w = (bfbits(f[7]) << 16) | bfbits(f[6]);
  *(uint4*)(o + off) = u;
}

// ---------------------------------------------------------------------------
// Packed attention mask (natural [b][q][k] layout):
//   out = hid|pad ? 0xFFFFFFFF : (bf16(pm[b,k,q])<<16 | bf16(pm[b,q,k]))
// ---------------------------------------------------------------------------
__global__ __launch_bounds__(256)
void mask_pack(const float* __restrict__ pm, const int* __restrict__ hid,
               const int* __restrict__ padm, uint32_t* __restrict__ out)
{
  __shared__ float tileT[128][65];   // [k-local][q-local]
  const int b = blockIdx.z, q0 = blockIdx.y * 64, k0 = blockIdx.x * 128;
  const int t = threadIdx.x;
  const size_t pb = (size_t)b << 20;
#pragma unroll
  for (int i = 0; i < 32; ++i) {     // stage pm[b][k0+r][q0+c]
    int idx = t + i * 256;
    int r = idx >> 6, c = idx & 63;
    tileT[r][c] = pm[pb + (size_t)(k0 + r) * 1024 + q0 + c];
  }
  __syncthreads();
#pragma unroll
  for (int i = 0; i < 32; ++i) {
    int idx = t + i * 256;           // 64 q x 128 k
    int q = idx >> 7, k = idx & 127;
    size_t src = pb + (size_t)(q0 + q) * 1024 + k0 + k;
    int msk = hid[src] | padm[b * 1024 + k0 + k];
    uint32_t u = 0xFFFFFFFFu;
    if (!msk) u = (bfbits(tileT[k][q]) << 16) | bfbits(pm[src]);
    out[src] = u;
  }
}

// ---------------------------------------------------------------------------
// GEMM: C[M,Nout] = A[M,K(kOff..kOff+kLen)] * W^T + bias   (bf16, f32 accum)
// 128 x BN tile, global_load_lds(16B) staging, 4 waves.
// MODE 0: bf16 store. MODE 1: relu+bf16. MODE 2: QKV scatter.
// MODE 3: f32 partial store (split-K slice z=blockIdx.z), no bias.
// ---------------------------------------------------------------------------
template<int MODE, int BN>
__global__ __launch_bounds__(256)
void gemm_bt(const bf16* __restrict__ A, const bf16* __restrict__ W,
             const float* __restrict__ bias, bf16* __restrict__ outb,
             float* __restrict__ outf, int M, int Nout, int K, int kLen)
{
  constexpr int NT = BN / 32;
  __shared__ bf16 As[128 * 64];
  __shared__ bf16 Bs[BN * 64];
  const int t = threadIdx.x, lane = t & 63, wave = t >> 6;
  const int m0 = blockIdx.y * 128, n0 = blockIdx.x * BN;
  const int kOff = blockIdx.z * kLen;
  if (MODE == 3) outf += (size_t)blockIdx.z * M * Nout;
  const int wr = wave >> 1, wc = wave & 1;
  const int frow = lane & 15, ksel = (lane >> 4) * 8;
  f32x4 acc[4 * NT] = {};
  const bf16* Ab = A + (size_t)m0 * K;
  const bf16* Wb = W + (size_t)n0 * K;

  for (int k0 = kOff; k0 < kOff + kLen; k0 += 64) {
    __syncthreads();
#pragma unroll
    for (int i = 0; i < 4; ++i) {
      int ib = i * 256 + wave * 64;
      int idx = ib + lane;
      gload16(Ab + (size_t)(idx >> 3) * K + k0 + (idx & 7) * 8, As + ib * 8);
    }
#pragma unroll
    for (int i = 0; i < BN / 32; ++i) {
      int ib = i * 256 + wave * 64;
      int idx = ib + lane;
      gload16(Wb + (size_t)(idx >> 3) * K + k0 + (idx & 7) * 8, Bs + ib * 8);
    }
    __syncthreads();
#pragma unroll
    for (int kk = 0; kk < 64; kk += 32) {
      bf16x8 af[4], bf_[NT];
#pragma unroll
      for (int mt = 0; mt < 4; ++mt)
        af[mt] = *(const bf16x8*)(As + (wr * 64 + mt * 16 + frow) * 64 + kk + ksel);
#pragma unroll
      for (int nt = 0; nt < NT; ++nt)
        bf_[nt] = *(const bf16x8*)(Bs + (wc * (BN / 2) + nt * 16 + frow) * 64 + kk + ksel);
#pragma unroll
      for (int mt = 0; mt < 4; ++mt)
#pragma unroll
        for (int nt = 0; nt < NT; ++nt)
          acc[mt * NT + nt] = __builtin_amdgcn_mfma_f32_16x16x32_bf16(
              af[mt], bf_[nt], acc[mt * NT + nt], 0, 0, 0);
    }
  }
  const int rb = (lane >> 4) * 4, cb = lane & 15;
#pragma unroll
  for (int mt = 0; mt < 4; ++mt)
#pragma unroll
    for (int nt = 0; nt < NT; ++nt) {
      f32x4 a = acc[mt * NT + nt];
#pragma unroll
      for (int r = 0; r < 4; ++r) {
        int row = m0 + wr * 64 + mt * 16 + rb + r;
        int col = n0 + wc * (BN / 2) + nt * 16 + cb;
        if (MODE == 3) {
          outf[(size_t)row * Nout + col] = a[r];
        } else {
          float v = a[r] + bias[col];
          if (MODE == 1) v = fmaxf(v, 0.f);
          if (MODE == 2) {
            int which = col >> 9, hh = (col >> 6) & 7, d = col & 63;
            int n = row >> 2, b = row & 3;
            size_t idx;
            if (which == 2)   // V transposed: [b][h][d][n]
              idx = (((size_t)(64 + b * 8 + hh)) << 16) + (size_t)d * 1024 + n;
            else              // Q,K: [which][b][h][n][d]
              idx = (((size_t)(which * 32 + b * 8 + hh)) << 16) + (size_t)n * 64 + d;
            outb[idx] = __float2bfloat16(v);
          } else {
            outb[(size_t)row * Nout + col] = __float2bfloat16(v);
          }
        }
      }
    }
}

// ---------------------------------------------------------------------------
// parent/child bias projections: pb[b,h,n] = x[n,b,:].Wp[h,:] + bp[h]
// ---------------------------------------------------------------------------
__global__ __launch_bounds__(256)
void pbcb_kernel(const float* __restrict__ x, const float* __restrict__ Wp,
                 const float* __restrict__ bp, const float* __restrict__ Wc,
                 const float* __restrict__ bc, float* __restrict__ pbo,
                 float* __restrict__ cbo)
{
  const int wave = threadIdx.x >> 6, lane = threadIdx.x & 63;
  const int m = blockIdx.x * 4 + wave;     // m = n*4 + b
  float xv[8];
  load8(x + (size_t)m * 512 + lane * 8, xv);
  const int n = m >> 2, b = m & 3;
#pragma unroll
  for (int hh = 0; hh < 8; ++hh) {
    float wp[8], wc[8];
    load8(Wp + (size_t)hh * 512 + lane * 8, wp);
    load8(Wc + (size_t)hh * 512 + lane * 8, wc);
    float ap = 0.f, ac = 0.f;
#pragma unroll
    for (int j = 0; j < 8; ++j) { ap += xv[j] * wp[j]; ac += xv[j] * wc[j]; }
#pragma unroll
    for (int off = 32; off; off >>= 1) {
      ap += __shfl_xor(ap, off);
      ac += __shfl_xor(ac, off);
    }
    if (lane == 0) {
      pbo[((size_t)b * 8 + hh) * 1024 + n] = ap + bp[hh];
      cbo[((size_t)b * 8 + hh) * 1024 + n] = ac + bc[hh];
    }
  }
}

// ---------------------------------------------------------------------------
// MFMA flash attention, S^T form. Block = 64 q of one (b,h); 4 waves x 16 q.
// S^T = K·Q^T so C-layout col = q: lane owns ONE q-row -> per-lane softmax
// state, zero broadcast shuffles (only 2 shfl_xor over the 4 key-groups).
// P written as packed b64 [q][k]; PV as O^T = V^T·P. Mask: natural [q][k]
// uint32 = (bf16 pmT <<16)|bf16 pm, 0xFFFFFFFF = masked, prefetched per tile.
// ---------------------------------------------------------------------------
__global__ __launch_bounds__(256, 2)
void attn_mfma(const bf16* __restrict__ qkv, const float* __restrict__ pbw,
               const float* __restrict__ cbw, const uint32_t* __restrict__ mpk,
               bf16* __restrict__ ctxo)
{
  __shared__ bf16 Kt[128][80];     // [key][d]
  __shared__ bf16 Vt[64][144];     // [d][key]
  __shared__ bf16 Ps[4][16][144];  // per-wave P [q][key]
  const int t = threadIdx.x, lane = t & 63, wave = t >> 6;
  const int g = lane >> 4, c = lane & 15;
  const int h = blockIdx.y, b = blockIdx.z;
  const int q0 = blockIdx.x * 64 + wave * 16;
  const size_t bh = (size_t)b * 8 + h;
  const bf16* Qp = qkv + (bh << 16);
  const bf16* Kp = qkv + ((32 + bh) << 16);
  const bf16* Vg = qkv + ((64 + bh) << 16);     // [64 d][1024 n]

  // Q B-fragment: B[n=q=c][k=g*8+j]
  bf16x8 qa0 = *(const bf16x8*)(Qp + (size_t)(q0 + c) * 64 + g * 8);
  bf16x8 qa1 = *(const bf16x8*)(Qp + (size_t)(q0 + c) * 64 + 32 + g * 8);

  const float pbq = pbw[bh * 1024 + q0 + c];
  const float cbq = cbw[bh * 1024 + q0 + c];
  const uint32_t* mrp = mpk + (((size_t)b * 1024 + q0 + c) << 10);

  f32x4 oacc[4] = {{0,0,0,0},{0,0,0,0},{0,0,0,0},{0,0,0,0}};
  float m = -1e30f, l = 0.f;

  for (int kt = 0; kt < 8; ++kt) {
    const int k0 = kt * 128;
    // ---- prefetch this tile's mask words (keys nt*16 + 4g + 0..3)
    uint4 mu[8];
#pragma unroll
    for (int nt = 0; nt < 8; ++nt)
      mu[nt] = *(const uint4*)(mrp + k0 + nt * 16 + 4 * g);
    __syncthreads();
#pragma unroll
    for (int i = 0; i < 4; ++i) {    // K tile
      int idx = t + i * 256;
      int r = idx >> 3, cc = idx & 7;
      *(uint4*)&Kt[r][cc * 8] = *(const uint4*)(Kp + (size_t)(k0 + r) * 64 + cc * 8);
    }
#pragma unroll
    for (int i = 0; i < 4; ++i) {    // V^T tile
      int idx = t + i * 256;
      int r = idx >> 4, cc = idx & 15;
      *(uint4*)&Vt[r][cc * 8] = *(const uint4*)(Vg + (size_t)r * 1024 + k0 + cc * 8);
    }
    __syncthreads();
    // ---- S^T = K·Q^T : lane gets col q=c, rows key = nt*16 + 4g + r
    f32x4 sacc[8];
#pragma unroll
    for (int nt = 0; nt < 8; ++nt) {
      f32x4 z = {0.f,0.f,0.f,0.f};
      bf16x8 k0f = *(const bf16x8*)&Kt[nt * 16 + c][g * 8];
      bf16x8 k1f = *(const bf16x8*)&Kt[nt * 16 + c][32 + g * 8];
      z = __builtin_amdgcn_mfma_f32_16x16x32_bf16(k0f, qa0, z, 0, 0, 0);
      z = __builtin_amdgcn_mfma_f32_16x16x32_bf16(k1f, qa1, z, 0, 0, 0);
      sacc[nt] = z;
    }
    // ---- bias + mask + per-lane online softmax
    float mx = -1e30f;
#pragma unroll
    for (int nt = 0; nt < 8; ++nt) {
      uint32_t uu[4] = {mu[nt].x, mu[nt].y, mu[nt].z, mu[nt].w};
#pragma unroll
      for (int r = 0; r < 4; ++r) {
        float s = sacc[nt][r] * 0.125f + bfhi(uu[r]) * pbq + bflo(uu[r]) * cbq;
        s = (uu[r] == 0xFFFFFFFFu) ? -1e30f : s;
        sacc[nt][r] = s;
        mx = fmaxf(mx, s);
      }
    }
    mx = fmaxf(mx, __shfl_xor(mx, 16));
    mx = fmaxf(mx, __shfl_xor(mx, 32));
    const float newm = fmaxf(m, mx);
    const float al = __expf(m - newm);
    float ps = 0.f;
#pragma unroll
    for (int nt = 0; nt < 8; ++nt) {
      float p0 = (sacc[nt][0] <= -1e29f) ? 0.f : __expf(sacc[nt][0] - newm);
      float p1 = (sacc[nt][1] <= -1e29f) ? 0.f : __expf(sacc[nt][1] - newm);
      float p2 = (sacc[nt][2] <= -1e29f) ? 0.f : __expf(sacc[nt][2] - newm);
      float p3 = (sacc[nt][3] <= -1e29f) ? 0.f : __expf(sacc[nt][3] - newm);
      ps += (p0 + p1) + (p2 + p3);
      uint2 w;
      w.x = (bfbits(p1) << 16) | bfbits(p0);
      w.y = (bfbits(p3) << 16) | bfbits(p2);
      *(uint2*)&Ps[wave][c][nt * 16 + 4 * g] = w;   // keys nt*16+4g..+3
    }
    ps += __shfl_xor(ps, 16);
    ps += __shfl_xor(ps, 32);
    l = l * al + ps;
    m = newm;
#pragma unroll
    for (int dt = 0; dt < 4; ++dt) {
      oacc[dt][0] *= al; oacc[dt][1] *= al;
      oacc[dt][2] *= al; oacc[dt][3] *= al;
    }
    // ---- PV: O^T[d][q] += sum_k V^T[d][k] * P[q][k]
#pragma unroll
    for (int dt = 0; dt < 4; ++dt) {
#pragma unroll
      for (int kc = 0; kc < 4; ++kc) {
        bf16x8 vf = *(const bf16x8*)&Vt[dt * 16 + c][kc * 32 + g * 8];
        bf16x8 pf = *(const bf16x8*)&Ps[wave][c][kc * 32 + g * 8];
        oacc[dt] = __builtin_amdgcn_mfma_f32_16x16x32_bf16(vf, pf, oacc[dt], 0, 0, 0);
      }
    }
  }
  const float inv = (l > 0.f) ? 1.f / l : 0.f;
  const int qg = q0 + c;
#pragma unroll
  for (int dt = 0; dt < 4; ++dt)
#pragma unroll
    for (int rg = 0; rg < 4; ++rg) {
      int d = dt * 16 + 4 * g + rg;
      ctxo[((size_t)qg * 4 + b) * 512 + h * 64 + d] =
          __float2bfloat16(oacc[dt][rg] * inv);
    }
}

// ---------------------------------------------------------------------------
// out = LayerNorm(a + p0 + p1 + bias) * g + be   (row = 512, wave per row)
// (p0+p1 = split-K GEMM partials, f32)
// ---------------------------------------------------------------------------
template<typename TA, typename TO>
__global__ __launch_bounds__(256)
void ln_res2(const TA* __restrict__ a, const float* __restrict__ p0,
             const float* __restrict__ p1, const float* __restrict__ bias,
             const float* __restrict__ g, const float* __restrict__ be,
             TO* __restrict__ out)
{
  const int wave = threadIdx.x >> 6, lane = threadIdx.x & 63;
  const int m = blockIdx.x * 4 + wave;
  const size_t base = (size_t)m * 512 + lane * 8;
  float va[8], f0[8], f1[8], bb[8];
  load8(a + base, va);
  load8(p0 + base, f0);
  load8(p1 + base, f1);
  load8(bias + lane * 8, bb);
  float v[8], s = 0.f;
#pragma unroll
  for (int j = 0; j < 8; ++j) { v[j] = va[j] + f0[j] + f1[j] + bb[j]; s += v[j]; }
#pragma unroll
  for (int off = 32; off; off >>= 1) s += __shfl_xor(s, off);
  const float mean = s * (1.f / 512.f);
  float q = 0.f;
#pragma unroll
  for (int j = 0; j < 8; ++j) { float d = v[j] - mean; q += d * d; }
#pragma unroll
  for (int off = 32; off; off >>= 1) q += __shfl_xor(q, off);
  const float rs = rsqrtf(q * (1.f / 512.f) + 1e-5f);
  float gv[8], bv[8];
  load8(g + lane * 8, gv);
  load8(be + lane * 8, bv);
#pragma unroll
  for (int j = 0; j < 8; ++j)
    store1(out + base + j, (v[j] - mean) * rs * gv[j] + bv[j]);
}

// ---------------------------------------------------------------------------
extern "C" void kernel_launch(void* const* d_in, const int* in_sizes, int n_in,
                              void* d_out, int out_size, void* d_ws, size_t ws_size,
                              hipStream_t stream)
{
  (void)in_sizes; (void)n_in; (void)out_size; (void)ws_size;
  const float* x    = (const float*)d_in[0];
  const float* pm   = (const float*)d_in[1];
  const int*   hid  = (const int*)d_in[2];
  const int*   padm = (const int*)d_in[3];
  const float* Wp   = (const float*)d_in[4];
  const float* bp   = (const float*)d_in[5];
  const float* Wc   = (const float*)d_in[6];
  const float* bc   = (const float*)d_in[7];
  const float* Wqkv = (const float*)d_in[8];
  const float* bqkv = (const float*)d_in[9];
  const float* Wo   = (const float*)d_in[10];
  const float* bo   = (const float*)d_in[11];
  const float* W1   = (const float*)d_in[12];
  const float* b1   = (const float*)d_in[13];
  const float* W2   = (const float*)d_in[14];
  const float* b2   = (const float*)d_in[15];
  const float* g1   = (const float*)d_in[16];
  const float* be1  = (const float*)d_in[17];
  const float* g2   = (const float*)d_in[18];
  const float* be2  = (const float*)d_in[19];

  // Workspace (max 48,496,640 B; lifetimes checked in journal):
  char* ws = (char*)d_ws;
  bf16*     qkvb  = (bf16*)    (ws);               // 12.58 MB (QKV gemm -> attn)
  float*    pbo   = (float*)   (ws + 12582912);    // 128 KB  (pbcb -> attn)
  float*    cbo   = (float*)   (ws + 12713984);    // 128 KB
  uint32_t* mpk   = (uint32_t*)(ws + 12845056);    // 16.78 MB (mask_pack -> attn)
  bf16*     ctx   = (bf16*)    (ws + 29622272);    // 4.19 MB (attn -> Wo gemm)
  float*    part  = (float*)   (ws);               // 16.78 MB split-K partials
                                                   //   (aliases qkvb+pbo+cbo+mpk-head,
                                                   //    all dead after attn / prev ln)
  bf16*     ff1   = (bf16*)    (ws + 16777216);    // 16.78 MB (aliases mpk tail + ctx,
                                                   //    both dead when FF1 runs)
  bf16*     y     = (bf16*)    (ws + 33816576);    // 4.19 MB (ln1 -> ln2)
  bf16*     xb    = (bf16*)    (ws + 38010880);    // 4.19 MB
  bf16*     wqkvb = (bf16*)    (ws + 42205184);    // 1.57 MB
  bf16*     wob   = (bf16*)    (ws + 43778048);    // 512 KB
  bf16*     w1b   = (bf16*)    (ws + 44302336);    // 2.10 MB
  bf16*     w2b   = (bf16*)    (ws + 46399488);    // 2.10 MB (end 48,496,640)
  float*    part1 = part + (size_t)4096 * 512;

  cvt5<<<2560, 256, 0, stream>>>(x, Wqkv, Wo, W1, W2, xb, wqkvb, wob, w1b, w2b);
  mask_pack<<<dim3(8, 16, 4), 256, 0, stream>>>(pm, hid, padm, mpk);
  pbcb_kernel<<<1024, 256, 0, stream>>>(x, Wp, bp, Wc, bc, pbo, cbo);
  gemm_bt<2, 128><<<dim3(12, 32), 256, 0, stream>>>(xb, wqkvb, bqkv, qkvb, nullptr, 4096, 1536, 512, 512);
  attn_mfma<<<dim3(16, 8, 4), 256, 0, stream>>>(qkvb, pbo, cbo, mpk, ctx);
  gemm_bt<3, 64><<<dim3(8, 32, 2), 256, 0, stream>>>(ctx, wob, nullptr, nullptr, part, 4096, 512, 512, 256);
  ln_res2<float, bf16><<<1024, 256, 0, stream>>>(x, part, part1, bo, g1, be1, y);
  gemm_bt<1, 128><<<dim3(16, 32), 256, 0, stream>>>(y, w1b, b1, ff1, nullptr, 4096, 2048, 512, 512);
  gemm_bt<3, 64><<<dim3(8, 32, 2), 256, 0, stream>>>(ff1, w2b, nullptr, nullptr, part, 4096, 512, 2048, 1024);
  ln_res2<bf16, float><<<1024, 256, 0, stream>>>(y, part, part1, b2, g2, be2, (float*)d_out);
}